// Round 7
// baseline (104.464 us; speedup 1.0000x reference)
//
#include <hip/hip_runtime.h>

// Problem constants
#define N_FILTERS 1024
#define B_TOTAL   1024
#define IMG       64            // H = W = 64
#define PAD_DIM   70            // 64 + 2*3 padded image side
// Xt layout in d_ws: fp16 [4900 pixels][1024 batches] (10 MB).
// bg = blockIdx&7 -> round-robin XCD dispatch pins a 128-batch slice per XCD:
// 4900 px * 256 B = 1.25 MB hot set, fits the 4 MB per-XCD L2.
//
// Work split (R6 post-mortem: latency-bound at 19% occupancy, 144-float acc):
// one WAVE = one (filter, pool-row). Pool row py consumes conv rows 3py..3py+2,
// which consume window rows 3py..3py+6 (7 rows x 10 cols). Accums: 3x6 fvec2
// = 36 floats -> ~75 VGPR live -> 4 waves/SIMD occupancy. Rows 3-6 read twice
// (traffic 210->294 MB, L2-served) in exchange for 2.5x occupancy.

typedef _Float16 half2_t __attribute__((ext_vector_type(2)));
typedef float    fvec2   __attribute__((ext_vector_type(2)));

// ---------------- prep: transpose X [1024 b][4096 px] -> Xt fp16 [px][b], + border zero ----
// blocks 0..511: transpose tile (64 px x 128 b). blocks 512..575: zero padded border.
__global__ __launch_bounds__(256) void prep_kernel(
    const float* __restrict__ X, _Float16* __restrict__ Xt)
{
    if (blockIdx.x < 512) {
        __shared__ float T[128 * 65];        // [b_local][px_local], stride 65
        const int pt = blockIdx.x & 63;      // pixel tile (64 pixels)
        const int bt = blockIdx.x >> 6;      // batch tile (128 batches)
        const int tx = threadIdx.x & 63, ty = threadIdx.x >> 6;

        #pragma unroll
        for (int pass = 0; pass < 32; ++pass) {
            int bl = pass * 4 + ty;          // lanes: consecutive pixels -> 256 B coalesced
            T[bl * 65 + tx] = X[(size_t)(bt * 128 + bl) * 4096 + pt * 64 + tx];
        }
        __syncthreads();
        #pragma unroll
        for (int pass = 0; pass < 16; ++pass) {
            int pl = pass * 4 + ty;          // pixel within tile
            int p  = pt * 64 + pl;
            int r  = p >> 6, c = p & 63;
            // lane tx packs batches (2tx, 2tx+1) -> one dword store, 256 B/wave
            half2_t h;
            h.x = (_Float16)T[(2 * tx) * 65 + pl];      // 2-way bank alias: free
            h.y = (_Float16)T[(2 * tx + 1) * 65 + pl];
            *(half2_t*)&Xt[(size_t)((r + 3) * PAD_DIM + (c + 3)) * 1024 + bt * 128 + 2 * tx] = h;
        }
    } else {
        // border zeroing: 804 border pixels x 2048 B
        const int bp = blockIdx.x - 512;     // 0..63
        for (int pp = bp; pp < PAD_DIM * PAD_DIM; pp += 64) {
            int r = pp / PAD_DIM, c = pp - r * PAD_DIM;
            if (r >= 3 && r < 67 && c >= 3 && c < 67) continue;
            unsigned int* q = (unsigned int*)Xt + (size_t)pp * 512;
            q[threadIdx.x] = 0u;
            q[threadIdx.x + 256] = 0u;
        }
    }
}

// ---------------- main: wave = (filter, pool-row), lanes = 2 batches each ----------------
// Block = 4 waves = 2 filters x 2 pool-rows, batches bg*128..bg*128+127.
__global__ __launch_bounds__(256, 4) void filters_main(
    const _Float16* __restrict__ Xt,   // [4900 px][1024 b] fp16
    const float*    __restrict__ W,    // [F][25]
    const float*    __restrict__ bias, // [F]
    const int*      __restrict__ pos,  // [F][2]
    float*          __restrict__ out)  // [B][4096] floats
{
    const int t    = threadIdx.x;
    const int lane = t & 63;
    const int py   = (t >> 6) & 1;                 // pool row 0/1
    const int fl   = t >> 7;                       // filter-in-block 0/1
    const int bg   = blockIdx.x & 7;               // batch group (128 batches) -> XCD pin
    const int fg   = blockIdx.x >> 3;              // filter group (2 filters), 0..511

    const int f  = fg * 2 + fl;
    const int sf = __builtin_amdgcn_readfirstlane(f);
    const int si = __builtin_amdgcn_readfirstlane(pos[2 * sf]);       // 0..59
    const int sj = __builtin_amdgcn_readfirstlane(pos[2 * sf + 1]);   // 0..59
    const int r0 = si + 3 * py;                    // first window row for this wave

    float wk[25];
    const float* wp = W + sf * 25;                 // scalar address -> s_load into SGPRs
    #pragma unroll
    for (int k = 0; k < 25; ++k) wk[k] = wp[k];

    // per-lane byte offset within a pixel's 2048 B batch row (2 batches = 4 B)
    const int laneByte = bg * 256 + lane * 4;

    fvec2 acc[18];                                 // 3 conv rows x 6 cols, batch pair
    #pragma unroll
    for (int k = 0; k < 18; ++k) acc[k] = (fvec2)0.0f;

    #pragma unroll
    for (int wrl = 0; wrl < 7; ++wrl) {            // 7 window rows for this pool row
        const char* rowp = (const char*)Xt
                         + (size_t)((r0 + wrl) * PAD_DIM + sj) * 2048 + laneByte;
        fvec2 in2[10];
        #pragma unroll
        for (int wc = 0; wc < 10; ++wc) {
            half2_t h = __builtin_bit_cast(half2_t,
                          *(const unsigned int*)(rowp + (size_t)wc * 2048));
            in2[wc].x = (float)h.x;
            in2[wc].y = (float)h.y;
        }
        // conv row y (0..2 within wave) uses window rows y..y+4
        #pragma unroll
        for (int y = 0; y < 3; ++y) {
            if (y >= ((wrl > 4) ? (wrl - 4) : 0) && y <= ((wrl < 2) ? wrl : 2)) {
                const int r = wrl - y;
                #pragma unroll
                for (int x = 0; x < 6; ++x) {
                    #pragma unroll
                    for (int c = 0; c < 5; ++c)
                        acc[y * 6 + x] = wk[r * 5 + c] * in2[x + c] + acc[y * 6 + x];
                }
            }
        }
    }

    // 3x3 maxpool over the 3x6 grid -> 1x2; bias after max
    const float bv = bias[sf];
    fvec2 m[2];
    #pragma unroll
    for (int px = 0; px < 2; ++px) {
        fvec2 u = acc[3 * px];
        #pragma unroll
        for (int y = 0; y < 3; ++y)
            #pragma unroll
            for (int dx = 0; dx < 3; ++dx) {
                fvec2 e = acc[y * 6 + 3 * px + dx];
                u.x = fmaxf(u.x, e.x);
                u.y = fmaxf(u.y, e.y);
            }
        m[px].x = u.x + bv;
        m[px].y = u.y + bv;
    }

    // out[b][f*4 + py*2 + {0,1}]; batch pair (b0, b0+1); 8 B stores, merge in L2
    const int b0 = bg * 128 + lane * 2;
    const size_t o0 = (size_t)b0 * 4096 + sf * 4 + py * 2;
    fvec2 s0; s0.x = m[0].x; s0.y = m[1].x;
    fvec2 s1; s1.x = m[0].y; s1.y = m[1].y;
    *(fvec2*)&out[o0]        = s0;
    *(fvec2*)&out[o0 + 4096] = s1;
}

extern "C" void kernel_launch(void* const* d_in, const int* in_sizes, int n_in,
                              void* d_out, int out_size, void* d_ws, size_t ws_size,
                              hipStream_t stream) {
    const float* X    = (const float*)d_in[0];
    const float* W    = (const float*)d_in[1];
    const float* bias = (const float*)d_in[2];
    const int*   pos  = (const int*)d_in[3];
    float* out = (float*)d_out;
    _Float16* Xt = (_Float16*)d_ws;        // 70*70*1024 fp16 = 10 MB

    prep_kernel<<<576, 256, 0, stream>>>(X, Xt);
    filters_main<<<4096, 256, 0, stream>>>(Xt, W, bias, pos, out);
}